// Round 2
// baseline (281.282 us; speedup 1.0000x reference)
//
#include <hip/hip_runtime.h>

// CosineLoss: out = mean_i( 1 - dot(a_i,b_i) / (||a_i||*||b_i||) )
// inputs: d_in[0]=cxr (N,D) f32, d_in[1]=ehr (N,D) f32; N=16384, D=2048.
//
// R5 diagnosis: R4 intended 16 loads in flight but VGPR_Count=36 proves the
// compiler interleaved load/FMA and kept only ~2 outstanding (same as
// R2/R3 -> same 2.7 TB/s delivered, warm-L3 == cold-HBM time => CU-side
// latency bound, not DRAM bound).
//
// R5: IDENTICAL geometry to R4 (1024 blocks x 256 thr, 4 rows/wave) with
// ONE change: sched_barrier(0) fences force all 16 row-loads to issue
// before any FMA consumes them (64 live dest regs -> compiler cannot
// collapse), and the next row's 16 loads are issued before the ~500-cyc
// shuffle chain so they fly during the reduce + next drain.
// Expect VGPR ~85. If time is flat at ~98us with VGPR~85, the ~2.7 TB/s
// read plateau is the chip ceiling for this op.

#define ROWS 16384
#define COLS_V4 512                 // float4 per row (D=2048)
#define BLOCK 256                   // 4 waves per block
#define WPB (BLOCK / 64)            // 4
#define GRID 1024                   // 4096 waves total
#define RPW (ROWS / (GRID * WPB))   // 4 consecutive rows per wave

__global__ __launch_bounds__(BLOCK, 4) void cosine_partial_kernel(
    const float4* __restrict__ A,
    const float4* __restrict__ B,
    float* __restrict__ partial) {
    const int t    = threadIdx.x;
    const int wave = t >> 6;
    const int lane = t & 63;
    const int row0 = (blockIdx.x * WPB + wave) * RPW;

    // lane-local base pointers (row0, this lane's float4 column)
    const float4* __restrict__ a = A + (size_t)row0 * COLS_V4 + lane;
    const float4* __restrict__ b = B + (size_t)row0 * COLS_V4 + lane;

    float4 va[8], vb[8];

    // prologue: issue all 16 loads of row 0 (a/b interleaved so early FMAs
    // can start draining at vmcnt(14), not vmcnt(0))
    #pragma unroll
    for (int c = 0; c < 8; ++c) {
        va[c] = a[(size_t)c * 64];
        vb[c] = b[(size_t)c * 64];
    }

    float wloss = 0.0f;   // meaningful in lane 0 only

    #pragma unroll
    for (int r = 0; r < RPW; ++r) {
        // fence: nothing crosses -- all 16 loads are issued before any FMA
        __builtin_amdgcn_sched_barrier(0);

        float d = 0.0f, na = 0.0f, nb = 0.0f;
        #pragma unroll
        for (int c = 0; c < 8; ++c) {
            d  += va[c].x * vb[c].x + va[c].y * vb[c].y
                + va[c].z * vb[c].z + va[c].w * vb[c].w;
            na += va[c].x * va[c].x + va[c].y * va[c].y
                + va[c].z * va[c].z + va[c].w * va[c].w;
            nb += vb[c].x * vb[c].x + vb[c].y * vb[c].y
                + vb[c].z * vb[c].z + vb[c].w * vb[c].w;
        }

        __builtin_amdgcn_sched_barrier(0);

        // issue next row's 16 loads into the just-freed registers BEFORE the
        // shuffle chain -- they fly during the ~500-cyc reduce and beyond.
        if (r + 1 < RPW) {
            const size_t off = (size_t)(r + 1) * COLS_V4;
            #pragma unroll
            for (int c = 0; c < 8; ++c) {
                va[c] = a[off + (size_t)c * 64];
                vb[c] = b[off + (size_t)c * 64];
            }
        }

        __builtin_amdgcn_sched_barrier(0);

        // wave reduce (once per 16KB row)
        #pragma unroll
        for (int offd = 32; offd > 0; offd >>= 1) {
            d  += __shfl_down(d,  offd, 64);
            na += __shfl_down(na, offd, 64);
            nb += __shfl_down(nb, offd, 64);
        }
        if (lane == 0) wloss += 1.0f - d * rsqrtf(na * nb);
    }

    __shared__ float s_loss[WPB];
    if (lane == 0) s_loss[wave] = wloss;
    __syncthreads();
    if (t == 0) {
        float s = 0.0f;
        #pragma unroll
        for (int w = 0; w < WPB; ++w) s += s_loss[w];
        partial[blockIdx.x] = s;
    }
}

__global__ __launch_bounds__(256) void cosine_reduce_kernel(
    const float* __restrict__ partial,
    float* __restrict__ out) {
    const int t = threadIdx.x;
    float s = partial[t] + partial[t + 256] + partial[t + 512] + partial[t + 768];
    #pragma unroll
    for (int off = 32; off > 0; off >>= 1) s += __shfl_down(s, off, 64);

    __shared__ float s_sum[4];
    const int wave = t >> 6;
    const int lane = t & 63;
    if (lane == 0) s_sum[wave] = s;
    __syncthreads();
    if (t == 0) {
        out[0] = (s_sum[0] + s_sum[1] + s_sum[2] + s_sum[3]) * (1.0f / (float)ROWS);
    }
}

extern "C" void kernel_launch(void* const* d_in, const int* in_sizes, int n_in,
                              void* d_out, int out_size, void* d_ws, size_t ws_size,
                              hipStream_t stream) {
    const float4* cxr = (const float4*)d_in[0];
    const float4* ehr = (const float4*)d_in[1];
    float* out     = (float*)d_out;
    float* partial = (float*)d_ws;   // GRID floats = 4 KB, fully overwritten

    cosine_partial_kernel<<<GRID, BLOCK, 0, stream>>>(cxr, ehr, partial);
    cosine_reduce_kernel<<<1, 256, 0, stream>>>(partial, out);
}